// Round 1
// baseline (90.590 us; speedup 1.0000x reference)
//
#include <hip/hip_runtime.h>
#include <stdint.h>

#define THREADS 256
#define COLS_PER_THREAD 4
#define COLS_PER_BLOCK (THREADS * COLS_PER_THREAD)  // 1024
#define RW 16   // qweight word-rows (K/8) handled per k-block

// Accumulate 8 nibbles of word w against 8 x values.
// Nibble j of w corresponds to k = r*8 + j (GPTQ packing: value j at bits [4j+3:4j]).
// lo holds nibbles 0,2,4,6 in bytes 0..3; hi holds nibbles 1,3,5,7.
// (float)((u >> 8k) & 0xFF) pattern-matches to v_cvt_f32_ubyteN on gfx950.
__device__ __forceinline__ float dot8(const float* __restrict__ xr, uint32_t w, float acc) {
    uint32_t lo = w & 0x0F0F0F0Fu;
    uint32_t hi = (w >> 4) & 0x0F0F0F0Fu;
    acc = fmaf(xr[0], (float)(lo & 0xFFu),         acc);
    acc = fmaf(xr[1], (float)(hi & 0xFFu),         acc);
    acc = fmaf(xr[2], (float)((lo >> 8) & 0xFFu),  acc);
    acc = fmaf(xr[3], (float)((hi >> 8) & 0xFFu),  acc);
    acc = fmaf(xr[4], (float)((lo >> 16) & 0xFFu), acc);
    acc = fmaf(xr[5], (float)((hi >> 16) & 0xFFu), acc);
    acc = fmaf(xr[6], (float)(lo >> 24),           acc);
    acc = fmaf(xr[7], (float)(hi >> 24),           acc);
    return acc;
}

__global__ __launch_bounds__(THREADS) void qmatvec4_kernel(
    const float* __restrict__ x,
    const uint32_t* __restrict__ qw,
    const float* __restrict__ scales,
    const float* __restrict__ zeros,
    const float* __restrict__ bias,
    float* __restrict__ out,
    int OUT)
{
    const int col = blockIdx.x * COLS_PER_BLOCK + threadIdx.x * COLS_PER_THREAD;
    const int r0  = blockIdx.y * RW;
    const uint4* qv = (const uint4*)qw;
    const int rowStride4 = OUT >> 2;

    float acc0 = 0.f, acc1 = 0.f, acc2 = 0.f, acc3 = 0.f;
    float xs = 0.f;  // sum of x over this k-slice (wave-uniform)

    #pragma unroll
    for (int i = 0; i < RW; ++i) {
        const int r = r0 + i;
        float xr[8];
        #pragma unroll
        for (int j = 0; j < 8; ++j) {
            xr[j] = x[r * 8 + j];   // uniform address -> scalar loads
            xs += xr[j];
        }
        uint4 w = qv[(size_t)r * rowStride4 + (col >> 2)];
        acc0 = dot8(xr, w.x, acc0);
        acc1 = dot8(xr, w.y, acc1);
        acc2 = dot8(xr, w.z, acc2);
        acc3 = dot8(xr, w.w, acc3);
    }

    float b0 = 0.f, b1 = 0.f, b2 = 0.f, b3 = 0.f;
    if (blockIdx.y == 0) {  // bias contributed exactly once per column
        b0 = bias[col + 0]; b1 = bias[col + 1];
        b2 = bias[col + 2]; b3 = bias[col + 3];
    }
    // contribution = scales*partial_xw - zeros*xsum_slice (+ bias once)
    atomicAdd(&out[col + 0], fmaf(scales[col + 0], acc0, b0) - zeros[col + 0] * xs);
    atomicAdd(&out[col + 1], fmaf(scales[col + 1], acc1, b1) - zeros[col + 1] * xs);
    atomicAdd(&out[col + 2], fmaf(scales[col + 2], acc2, b2) - zeros[col + 2] * xs);
    atomicAdd(&out[col + 3], fmaf(scales[col + 3], acc3, b3) - zeros[col + 3] * xs);
}

extern "C" void kernel_launch(void* const* d_in, const int* in_sizes, int n_in,
                              void* d_out, int out_size, void* d_ws, size_t ws_size,
                              hipStream_t stream) {
    const float*    x      = (const float*)d_in[0];
    const uint32_t* qw     = (const uint32_t*)d_in[1];
    const float*    scales = (const float*)d_in[2];
    const float*    zeros  = (const float*)d_in[3];
    const float*    bias   = (const float*)d_in[4];
    float*          out    = (float*)d_out;

    const int OUT = in_sizes[4];           // 8192
    const int R   = in_sizes[1] / OUT;     // 1024 packed word-rows

    // d_out is re-poisoned to 0xAA before every timed launch -> zero it.
    hipMemsetAsync(d_out, 0, (size_t)out_size * sizeof(float), stream);

    dim3 grid(OUT / COLS_PER_BLOCK, R / RW);  // (8, 64) = 512 blocks
    qmatvec4_kernel<<<grid, THREADS, 0, stream>>>(x, qw, scales, zeros, bias, out, OUT);
}

// Round 2
// 88.054 us; speedup vs baseline: 1.0288x; 1.0288x over previous
//
#include <hip/hip_runtime.h>
#include <stdint.h>

#define THREADS 256
#define COLS_PER_THREAD 4
#define COLS_PER_BLOCK (THREADS * COLS_PER_THREAD)  // 1024
#define RW 16          // qweight word-rows (K/8) per k-block
#define KSPLIT 64      // number of k-blocks (R / RW = 1024/16)
#define OUTF 8192
#define NPART (KSPLIT * OUTF)   // float count of partial matrix in ws

// Accumulate 8 nibbles of word w against 8 x values.
// Nibble j of w is k = r*8 + j. lo = nibbles 0,2,4,6 ; hi = nibbles 1,3,5,7.
// (float)((u >> 8k) & 0xFF) pattern-matches to v_cvt_f32_ubyteN.
__device__ __forceinline__ float dot8(const float* __restrict__ xr, uint32_t w, float acc) {
    uint32_t lo = w & 0x0F0F0F0Fu;
    uint32_t hi = (w >> 4) & 0x0F0F0F0Fu;
    acc = fmaf(xr[0], (float)(lo & 0xFFu),         acc);
    acc = fmaf(xr[1], (float)(hi & 0xFFu),         acc);
    acc = fmaf(xr[2], (float)((lo >> 8) & 0xFFu),  acc);
    acc = fmaf(xr[3], (float)((hi >> 8) & 0xFFu),  acc);
    acc = fmaf(xr[4], (float)((lo >> 16) & 0xFFu), acc);
    acc = fmaf(xr[5], (float)((hi >> 16) & 0xFFu), acc);
    acc = fmaf(xr[6], (float)(lo >> 24),           acc);
    acc = fmaf(xr[7], (float)(hi >> 24),           acc);
    return acc;
}

// Kernel A: raw partial dot products per k-block. No atomics, no epilogue.
// ws layout: partial[kb][col] for kb in [0,64), col in [0,8192); then xsum[kb] at NPART+kb.
__global__ __launch_bounds__(THREADS) void qmatvec4_partial(
    const float* __restrict__ x,
    const uint32_t* __restrict__ qw,
    float* __restrict__ ws)
{
    const int col = blockIdx.x * COLS_PER_BLOCK + threadIdx.x * COLS_PER_THREAD;
    const int kb  = blockIdx.y;
    const int r0  = kb * RW;
    const uint4* qv = (const uint4*)qw;

    float acc0 = 0.f, acc1 = 0.f, acc2 = 0.f, acc3 = 0.f;
    float xs = 0.f;  // sum of x over this k-slice (block-uniform)

    #pragma unroll
    for (int i = 0; i < RW; ++i) {
        const int r = r0 + i;
        float xr[8];
        #pragma unroll
        for (int j = 0; j < 8; ++j) {
            xr[j] = x[r * 8 + j];   // uniform address -> scalar loads
            xs += xr[j];
        }
        uint4 w = qv[(size_t)r * (OUTF / 4) + (col >> 2)];
        acc0 = dot8(xr, w.x, acc0);
        acc1 = dot8(xr, w.y, acc1);
        acc2 = dot8(xr, w.z, acc2);
        acc3 = dot8(xr, w.w, acc3);
    }

    float4 p = make_float4(acc0, acc1, acc2, acc3);
    ((float4*)ws)[((size_t)kb * OUTF + col) >> 2] = p;   // coalesced 16B store

    if (threadIdx.x == 0 && blockIdx.x == 0)
        ws[NPART + kb] = xs;
}

// Kernel B: reduce 64 partials per column + epilogue. Each output written exactly once.
__global__ __launch_bounds__(THREADS) void qmatvec4_reduce(
    const float* __restrict__ ws,
    const float* __restrict__ scales,
    const float* __restrict__ zeros,
    const float* __restrict__ bias,
    float* __restrict__ out)
{
    const int col = blockIdx.x * THREADS + threadIdx.x;

    float xsum = 0.f;
    #pragma unroll
    for (int kb = 0; kb < KSPLIT; ++kb)
        xsum += ws[NPART + kb];          // uniform -> scalar/broadcast loads

    float s = 0.f;
    #pragma unroll 16
    for (int kb = 0; kb < KSPLIT; ++kb)
        s += ws[(size_t)kb * OUTF + col];  // coalesced across the wave

    out[col] = fmaf(scales[col], s, bias[col]) - zeros[col] * xsum;
}

extern "C" void kernel_launch(void* const* d_in, const int* in_sizes, int n_in,
                              void* d_out, int out_size, void* d_ws, size_t ws_size,
                              hipStream_t stream) {
    const float*    x      = (const float*)d_in[0];
    const uint32_t* qw     = (const uint32_t*)d_in[1];
    const float*    scales = (const float*)d_in[2];
    const float*    zeros  = (const float*)d_in[3];
    const float*    bias   = (const float*)d_in[4];
    float*          out    = (float*)d_out;
    float*          ws     = (float*)d_ws;

    dim3 gridA(OUTF / COLS_PER_BLOCK, KSPLIT);   // (8, 64) = 512 blocks
    qmatvec4_partial<<<gridA, THREADS, 0, stream>>>(x, qw, ws);

    qmatvec4_reduce<<<OUTF / THREADS, THREADS, 0, stream>>>(ws, scales, zeros, bias, out);
}